// Round 1
// 553.882 us; speedup vs baseline: 1.6231x; 1.6231x over previous
//
#include <hip/hip_runtime.h>

// Problem geometry (fixed by reference):
//   x: (2, 32, 96,96,96) fp32; W: (1024,1024) fp32 [o][k]; bias: (1024,)
//   P=4 -> T=64, Q = 24^3 = 13824, spatial s = t*Q + q
//   GEMM: M=55296 (b,g,q), K=1024 (k=j*32+c), N=1024 (o)
//   A[m,k] = x[b][c][t_src*Q + q],  t_src = (32g + j + 48) & 63  (j = k>>5, c = k&31)
//   out[b][o&31][tt*Q + q] = Y[m,o] + bias[o],  tt = (32g + (o>>5) + 48) & 63
//
// V2 strategy: the old single-kernel version was issue-bound (40 VMEM + ~200 VALU
// cvt ops per 16 MFMA; MfmaUtil 7.3%). Split into:
//   K1: pre-pass  -> Abf [M][K] bf16 (113 MB, ws) + Wbf [N][K] bf16 (2 MB, ws).
//       Converts each element exactly once; gives A k-contiguous rows.
//   K2: m97-style LDS-staged bf16 GEMM (128x128x64, global_load_lds w16,
//       ds_read_b128 frags, 2-barrier loop) with fused scatter epilogue.

#define NSPAT 884736   // 96^3
#define QQ    13824    // 24^3
#define MTOT  55296
#define KK    1024

#define NBLK_XC 27648  // (55296/32) m-tiles * (1024/64) k-tiles
#define NBLK_W  256    // 1024*1024 / (256*16)

typedef __attribute__((ext_vector_type(4))) float f32x4;
typedef __attribute__((ext_vector_type(8))) short bf16x8;

__device__ __forceinline__ short f2bf(float f) {
  // round-to-nearest-even fp32 -> bf16 (inputs finite)
  unsigned u = __builtin_bit_cast(unsigned, f);
  u += 0x7fff + ((u >> 16) & 1);
  return (short)(u >> 16);
}

__device__ __forceinline__ void async16(short* lds, const short* g) {
  // global -> LDS direct copy, 16 B per lane; LDS dest = wave-uniform base + lane*16
  __builtin_amdgcn_global_load_lds(
      (const __attribute__((address_space(1))) unsigned*)g,
      (__attribute__((address_space(3))) unsigned*)lds, 16, 0, 0);
}

// ---------------------------------------------------------------------------
// K1: build Abf[m][k] (bf16) from x, and Wbf[n][k] (bf16) from W.
// A-blocks: 32 m x 64 k per block; thread = (mi = tid&31, koct = tid>>5).
// Reads: 128 B (32 consecutive q) per (c,t)-plane access; writes 16 B/lane,
// 128 B/row assembled across koct lanes.
// ---------------------------------------------------------------------------
__global__ __launch_bounds__(256)
void convert_pre(const float* __restrict__ x, const float* __restrict__ Wm,
                 short* __restrict__ Abf, short* __restrict__ Wbf) {
  const int bid = blockIdx.x;
  const int tid = threadIdx.x;
  if (bid < NBLK_XC) {
    const int kb  = bid & 15;          // k-tile of 64
    const int mt  = bid >> 4;          // m-tile of 32 (1728 of them)
    const int mi  = tid & 31;
    const int m   = mt * 32 + mi;
    const int seg = mt / 432;          // 432 m-tiles per (b,g) segment
    const int q   = m - seg * 13824;
    const int bb  = seg >> 1;
    const int g   = seg & 1;
    const int k0t = kb * 64 + (tid >> 5) * 8;  // thread's 8-k octet (same j)
    const int j   = k0t >> 5;
    const int tsrc = ((g << 5) + j + 48) & 63;
    const int cb  = k0t & 31;
    const float* src = x + (size_t)bb * 32 * NSPAT + (size_t)tsrc * QQ + q;
    bf16x8 f;
#pragma unroll
    for (int t = 0; t < 8; t++)
      f[t] = f2bf(src[(size_t)(cb + t) * NSPAT]);
    *(bf16x8*)(Abf + (size_t)m * KK + k0t) = f;
  } else {
    // W convert: 16 contiguous elements per thread
    const int base = (bid - NBLK_XC) * 4096 + tid * 16;
#pragma unroll
    for (int h = 0; h < 2; h++) {
      const f32x4 a = *(const f32x4*)(Wm + base + h * 8);
      const f32x4 b = *(const f32x4*)(Wm + base + h * 8 + 4);
      bf16x8 f;
#pragma unroll
      for (int t = 0; t < 4; t++) { f[t] = f2bf(a[t]); f[t + 4] = f2bf(b[t]); }
      *(bf16x8*)(Wbf + base + h * 8) = f;
    }
  }
}

// ---------------------------------------------------------------------------
// K2: bf16 GEMM, m97 structure. Tile 128x128, BK=64, 4 waves (2x2 of 64x64),
// single LDS buffer, stage -> sync -> 32 MFMA -> sync.
// A = Abf [M][K] row-major, B = Wbf [N][K] row-major (B^T form).
// ---------------------------------------------------------------------------
__global__ __launch_bounds__(256, 2)
void swin_mfma(const short* __restrict__ A, const short* __restrict__ Bw,
               const float* __restrict__ bias, float* __restrict__ out) {
  __shared__ __align__(16) short As[128 * 64];
  __shared__ __align__(16) short Bs[128 * 64];

  const int bid = blockIdx.x;
  const int nt  = bid & 7;     // n fastest: 8 sibling n-tiles share the A panel
  const int mt  = bid >> 3;
  const int seg = mt / 108;    // 108 m-tiles(128) per (b,g) segment
  const int q0  = (mt - seg * 108) * 128;
  const int bb  = seg >> 1;
  const int g   = seg & 1;
  const int m0  = mt * 128;
  const int n0  = nt * 128;

  const int tid  = threadIdx.x;
  const int wv   = tid >> 6;
  const int lane = tid & 63;
  const int wr   = wv >> 1;    // wave row (m)
  const int wc   = wv & 1;     // wave col (n)
  const int lm   = lane & 15;
  const int quad = lane >> 4;

  // staging: wave wv owns rows [wv*32, wv*32+32), 4 issues of 8 rows each;
  // lane l -> row +(l>>3), k-offset (l&7)*8 (16 B) — matches LDS base+lane*16
  const int srow  = wv * 32 + (lane >> 3);
  const int skoff = (lane & 7) * 8;
  const short* aG = A  + (size_t)(m0 + srow) * KK + skoff;
  const short* bG = Bw + (size_t)(n0 + srow) * KK + skoff;
  short* aL = As + wv * 32 * 64;
  short* bL = Bs + wv * 32 * 64;

  f32x4 acc[4][4];
#pragma unroll
  for (int i = 0; i < 4; i++)
#pragma unroll
    for (int jj = 0; jj < 4; jj++) {
      f32x4 z = {0.f, 0.f, 0.f, 0.f};
      acc[i][jj] = z;
    }

  for (int kt = 0; kt < 16; kt++) {
    const int kof = kt * 64;
#pragma unroll
    for (int is = 0; is < 4; is++) {
      async16(aL + is * 8 * 64, aG + kof + (size_t)is * 8 * KK);
      async16(bL + is * 8 * 64, bG + kof + (size_t)is * 8 * KK);
    }
    __syncthreads();  // compiler drains vmcnt(0) before s_barrier
#pragma unroll
    for (int ks = 0; ks < 2; ks++) {
      bf16x8 af[4], bfr[4];
#pragma unroll
      for (int i = 0; i < 4; i++)
        af[i] = *(const bf16x8*)(As + (wr * 64 + i * 16 + lm) * 64 + ks * 32 + quad * 8);
#pragma unroll
      for (int jj = 0; jj < 4; jj++)
        bfr[jj] = *(const bf16x8*)(Bs + (wc * 64 + jj * 16 + lm) * 64 + ks * 32 + quad * 8);
#pragma unroll
      for (int i = 0; i < 4; i++)
#pragma unroll
        for (int jj = 0; jj < 4; jj++)
          acc[i][jj] = __builtin_amdgcn_mfma_f32_16x16x32_bf16(af[i], bfr[jj], acc[i][jj], 0, 0, 0);
    }
    __syncthreads();
  }

  // Epilogue: D row (quad*4+r) -> q (contiguous), col (lm) -> o; scatter by o
  float* ob = out + (size_t)bb * 32 * NSPAT;
#pragma unroll
  for (int jj = 0; jj < 4; jj++) {
    const int o  = n0 + wc * 64 + jj * 16 + lm;
    const float bv = bias[o];
    const int so = o >> 5;
    const int cc = o & 31;
    const int tt = ((g << 5) + so + 48) & 63;
    float* orow = ob + (size_t)cc * NSPAT + (size_t)tt * QQ + q0;
#pragma unroll
    for (int i = 0; i < 4; i++) {
      const int mb = wr * 64 + i * 16 + quad * 4;
      f32x4 v = acc[i][jj];
      v += bv;
      *(f32x4*)(orow + mb) = v;  // 16B-aligned
    }
  }
}

// ---------------------------------------------------------------------------
// Fallback (previous verified kernel) in case ws is too small for Abf+Wbf.
// ---------------------------------------------------------------------------
__global__ __launch_bounds__(256, 2)
void swin_gemm(const float* __restrict__ x, const float* __restrict__ Wm,
               const float* __restrict__ bias, float* __restrict__ out) {
  const int bid = blockIdx.x;
  const int nt  = bid & 7;
  const int mt  = bid >> 3;
  const int seg = mt / 108;
  const int q0  = (mt - seg * 108) * 128;
  const int bb  = seg >> 1;
  const int g   = seg & 1;

  const int tid  = threadIdx.x;
  const int wv   = tid >> 6;
  const int wr   = wv >> 1;
  const int wc   = wv & 1;
  const int lane = tid & 63;
  const int lm   = lane & 15;
  const int quad = lane >> 4;

  const int n0 = nt * 128 + wc * 64;

  int aoff[4];
#pragma unroll
  for (int i = 0; i < 4; i++)
    aoff[i] = (quad * 8) * NSPAT + q0 + wr * 64 + i * 16 + lm;

  const float* wptr[4];
#pragma unroll
  for (int j = 0; j < 4; j++)
    wptr[j] = Wm + (size_t)(n0 + j * 16 + lm) * 1024 + quad * 8;

  f32x4 acc[4][4];
#pragma unroll
  for (int i = 0; i < 4; i++)
#pragma unroll
    for (int j = 0; j < 4; j++) {
      f32x4 z = {0.f, 0.f, 0.f, 0.f};
      acc[i][j] = z;
    }

  const float* xb = x + (size_t)bb * 32 * NSPAT;

  for (int kc = 0; kc < 32; kc++) {
    const int t_src = ((g << 5) + kc + 48) & 63;
    const float* xs = xb + (size_t)t_src * QQ;

    bf16x8 af[4];
#pragma unroll
    for (int i = 0; i < 4; i++) {
      float v[8];
#pragma unroll
      for (int t = 0; t < 8; t++)
        v[t] = xs[aoff[i] + t * NSPAT];
      bf16x8 f;
#pragma unroll
      for (int t = 0; t < 8; t++) f[t] = f2bf(v[t]);
      af[i] = f;
    }

    bf16x8 bfr[4];
#pragma unroll
    for (int j = 0; j < 4; j++) {
      const float* wp = wptr[j] + kc * 32;
      const f32x4 w0 = *(const f32x4*)(wp);
      const f32x4 w1 = *(const f32x4*)(wp + 4);
      bf16x8 f;
#pragma unroll
      for (int t = 0; t < 4; t++) { f[t] = f2bf(w0[t]); f[t + 4] = f2bf(w1[t]); }
      bfr[j] = f;
    }

#pragma unroll
    for (int i = 0; i < 4; i++)
#pragma unroll
      for (int j = 0; j < 4; j++)
        acc[i][j] = __builtin_amdgcn_mfma_f32_16x16x32_bf16(af[i], bfr[j], acc[i][j], 0, 0, 0);
  }

  float* ob = out + (size_t)bb * 32 * NSPAT;
#pragma unroll
  for (int j = 0; j < 4; j++) {
    const int o  = n0 + j * 16 + lm;
    const float bv = bias[o];
    const int so = o >> 5;
    const int cc = o & 31;
    const int tt = ((g << 5) + so + 48) & 63;
    float* orow = ob + (size_t)cc * NSPAT + (size_t)tt * QQ + q0;
#pragma unroll
    for (int i = 0; i < 4; i++) {
      const int mb = wr * 64 + i * 16 + quad * 4;
      f32x4 v = acc[i][j];
      v += bv;
      *(f32x4*)(orow + mb) = v;
    }
  }
}

extern "C" void kernel_launch(void* const* d_in, const int* in_sizes, int n_in,
                              void* d_out, int out_size, void* d_ws, size_t ws_size,
                              hipStream_t stream) {
  const float* x    = (const float*)d_in[0];
  const float* Wm   = (const float*)d_in[1];
  const float* bias = (const float*)d_in[2];
  float* out        = (float*)d_out;

  const size_t need = (size_t)MTOT * KK * 2 + (size_t)KK * KK * 2;  // 115.3 MB
  if (ws_size >= need) {
    short* Abf = (short*)d_ws;
    short* Wbf = (short*)d_ws + (size_t)MTOT * KK;
    convert_pre<<<dim3(NBLK_XC + NBLK_W), dim3(256), 0, stream>>>(x, Wm, Abf, Wbf);
    swin_mfma<<<dim3(432 * 8), dim3(256), 0, stream>>>(Abf, Wbf, bias, out);
  } else {
    swin_gemm<<<dim3(432 * 8), dim3(256), 0, stream>>>(x, Wm, bias, out);
  }
}

// Round 3
// 530.375 us; speedup vs baseline: 1.6950x; 1.0443x over previous
//
#include <hip/hip_runtime.h>

// Problem geometry (fixed by reference):
//   x: (2, 32, 96,96,96) fp32; W: (1024,1024) fp32 [o][k]; bias: (1024,)
//   P=4 -> T=64, Q = 24^3 = 13824, spatial s = t*Q + q
//   GEMM: M=55296 (b,g,q), K=1024 (k=j*32+c), N=1024 (o)
//   A[m,k] = x[b][c][t_src*Q + q],  t_src = (32g + j + 48) & 63  (j = k>>5, c = k&31)
//   out[b][o&31][tt*Q + q] = Y[m,o] + bias[o],  tt = (32g + (o>>5) + 48) & 63
//
// V3 (resubmit; round-2 bench died to container infra, source statically
// re-audited: bounds/alignment/bijectivity all OK):
//   - Abf/Wbf stored as contiguous 128x64 TILES in the GEMM's exact LDS image
//     order -> staging reads contiguous 4KB/wave-issue; prepass writes full
//     128B lines.
//   - XCD-grouping swizzle: hw bid -> (xcd = bid&7) owns contiguous mt range,
//     all 8 sibling n-tiles on same XCD -> A panel fetched into ONE L2.

#define NSPAT 884736   // 96^3
#define QQ    13824    // 24^3
#define MTOT  55296
#define KK    1024
#define TS    8192     // shorts per 128x64 tile (16 KB)

#define NBLK_A  6912   // 432 m-tiles * 16 k-tiles
#define NBLK_W  128    // 8 n-tiles * 16 k-tiles

typedef __attribute__((ext_vector_type(4))) float f32x4;
typedef __attribute__((ext_vector_type(8))) short bf16x8;

__device__ __forceinline__ short f2bf(float f) {
  // round-to-nearest-even fp32 -> bf16 (inputs finite)
  unsigned u = __builtin_bit_cast(unsigned, f);
  u += 0x7fff + ((u >> 16) & 1);
  return (short)(u >> 16);
}

__device__ __forceinline__ void async16(short* lds, const short* g) {
  // global -> LDS direct copy, 16 B per lane; LDS dest = wave-uniform base + lane*16
  __builtin_amdgcn_global_load_lds(
      (const __attribute__((address_space(1))) unsigned*)g,
      (__attribute__((address_space(3))) unsigned*)lds, 16, 0, 0);
}

// ---------------------------------------------------------------------------
// K1: build tiled Abf / Wbf (bf16).
// A-block = one (mt,kt) tile: 128 m x 64 k. Thread (rg=t>>3, oc=t&7) owns
// rows rg*4..rg*4+3 at k-octet oc: 8 coalesced f32x4 reads (8 planes x 128B
// per instr), 4 bf16x8 writes (8 full 128B lines per instr).
// ---------------------------------------------------------------------------
__global__ __launch_bounds__(256)
void convert_pre(const float* __restrict__ x, const float* __restrict__ Wm,
                 short* __restrict__ Abf, short* __restrict__ Wbf) {
  const int bid = blockIdx.x;
  const int tid = threadIdx.x;
  if (bid < NBLK_A) {
    const int mt = bid >> 4;
    const int kt = bid & 15;
    const int seg = mt / 108;
    const int q0  = (mt - seg * 108) * 128;
    const int bb  = seg >> 1;
    const int g   = seg & 1;

    const int rg = tid >> 3;          // 0..31: row group of 4
    const int oc = tid & 7;           // 0..7: k-octet within 64
    const int jp    = oc >> 2;        // j within tile (0..1)
    const int cbase = (oc & 3) * 8;
    const int tsrc  = ((g << 5) + kt * 2 + jp + 48) & 63;

    const float* base = x + ((size_t)bb * 32 + cbase) * NSPAT
                          + (size_t)tsrc * QQ + q0 + rg * 4;
    bf16x8 o[4];
#pragma unroll
    for (int tt = 0; tt < 8; tt++) {
      const f32x4 v = *(const f32x4*)(base + (size_t)tt * NSPAT);
#pragma unroll
      for (int r = 0; r < 4; r++) o[r][tt] = f2bf(v[r]);
    }
    short* dst = Abf + (size_t)(mt * 16 + kt) * TS + (rg * 4) * 64 + oc * 8;
#pragma unroll
    for (int r = 0; r < 4; r++)
      *(bf16x8*)(dst + r * 64) = o[r];
  } else {
    // W-block = one (nt,kt) tile: rows n' 0..127, k' 0..63
    const int wb = bid - NBLK_A;      // == nt*16 + kt
    const int nt = wb >> 4;
    const int kt = wb & 15;
    const int n0 = nt * 128;
#pragma unroll
    for (int it = 0; it < 4; it++) {
      const int idx = it * 256 + tid;     // octet index in tile
      const int row = idx >> 3;
      const int oc2 = idx & 7;
      const float* wsrc = Wm + (size_t)(n0 + row) * 1024 + kt * 64 + oc2 * 8;
      const f32x4 a = *(const f32x4*)(wsrc);
      const f32x4 b = *(const f32x4*)(wsrc + 4);
      bf16x8 f;
#pragma unroll
      for (int t = 0; t < 4; t++) { f[t] = f2bf(a[t]); f[t + 4] = f2bf(b[t]); }
      *(bf16x8*)(Wbf + (size_t)wb * TS + row * 64 + oc2 * 8) = f;
    }
  }
}

// ---------------------------------------------------------------------------
// K2: bf16 GEMM, m97 structure. Tile 128x128, BK=64, 4 waves (2x2 of 64x64),
// single LDS buffer, stage -> sync -> 32 MFMA -> sync.
// A/B in tiled layout: tile (mt*16+kt) / (nt*16+kt), 8192 shorts each, linear
// in the LDS image order -> staging reads are contiguous 4KB per wave-issue.
// ---------------------------------------------------------------------------
__global__ __launch_bounds__(256, 2)
void swin_mfma(const short* __restrict__ A, const short* __restrict__ Bw,
               const float* __restrict__ bias, float* __restrict__ out) {
  __shared__ __align__(16) short As[128 * 64];
  __shared__ __align__(16) short Bs[128 * 64];

  // XCD-grouping swizzle: grid 3456 = 8 xcd * 432; hw round-robins bid&7 over
  // XCDs -> give each XCD a contiguous logical range (54 mt x 8 nt).
  const int b0 = blockIdx.x;
  const int logical = (b0 & 7) * 432 + (b0 >> 3);
  const int nt = logical & 7;     // n fastest: siblings share the A panel
  const int mt = logical >> 3;
  const int seg = mt / 108;
  const int q0  = (mt - seg * 108) * 128;
  const int bb  = seg >> 1;
  const int g   = seg & 1;
  const int n0  = nt * 128;

  const int tid  = threadIdx.x;
  const int wv   = tid >> 6;
  const int lane = tid & 63;
  const int wr   = wv >> 1;    // wave row (m)
  const int wc   = wv & 1;     // wave col (n)
  const int lm   = lane & 15;
  const int quad = lane >> 4;

  // staging: tiled-contiguous; wave wv covers tile bytes [wv*4KB, +4KB)
  const short* aT = A  + (size_t)mt * 16 * TS + wv * 2048 + lane * 8;
  const short* bT = Bw + (size_t)nt * 16 * TS + wv * 2048 + lane * 8;
  short* aL = As + wv * 32 * 64;
  short* bL = Bs + wv * 32 * 64;

  f32x4 acc[4][4];
#pragma unroll
  for (int i = 0; i < 4; i++)
#pragma unroll
    for (int jj = 0; jj < 4; jj++) {
      f32x4 z = {0.f, 0.f, 0.f, 0.f};
      acc[i][jj] = z;
    }

  for (int kt = 0; kt < 16; kt++) {
    const size_t kof = (size_t)kt * TS;
#pragma unroll
    for (int is = 0; is < 4; is++) {
      async16(aL + is * 8 * 64, aT + kof + is * 512);
      async16(bL + is * 8 * 64, bT + kof + is * 512);
    }
    __syncthreads();  // compiler drains vmcnt(0) before s_barrier
#pragma unroll
    for (int ks = 0; ks < 2; ks++) {
      bf16x8 af[4], bfr[4];
#pragma unroll
      for (int i = 0; i < 4; i++)
        af[i] = *(const bf16x8*)(As + (wr * 64 + i * 16 + lm) * 64 + ks * 32 + quad * 8);
#pragma unroll
      for (int jj = 0; jj < 4; jj++)
        bfr[jj] = *(const bf16x8*)(Bs + (wc * 64 + jj * 16 + lm) * 64 + ks * 32 + quad * 8);
#pragma unroll
      for (int i = 0; i < 4; i++)
#pragma unroll
        for (int jj = 0; jj < 4; jj++)
          acc[i][jj] = __builtin_amdgcn_mfma_f32_16x16x32_bf16(af[i], bfr[jj], acc[i][jj], 0, 0, 0);
    }
    __syncthreads();
  }

  // Epilogue: D row (quad*4+r) -> q (contiguous), col (lm) -> o; scatter by o
  float* ob = out + (size_t)bb * 32 * NSPAT;
#pragma unroll
  for (int jj = 0; jj < 4; jj++) {
    const int o  = n0 + wc * 64 + jj * 16 + lm;
    const float bv = bias[o];
    const int so = o >> 5;
    const int cc = o & 31;
    const int tt = ((g << 5) + so + 48) & 63;
    float* orow = ob + (size_t)cc * NSPAT + (size_t)tt * QQ + q0;
#pragma unroll
    for (int i = 0; i < 4; i++) {
      const int mb = wr * 64 + i * 16 + quad * 4;
      f32x4 v = acc[i][jj];
      v += bv;
      *(f32x4*)(orow + mb) = v;  // 16B-aligned
    }
  }
}

// ---------------------------------------------------------------------------
// Fallback (round-0 verified kernel) in case ws is too small.
// ---------------------------------------------------------------------------
__global__ __launch_bounds__(256, 2)
void swin_gemm(const float* __restrict__ x, const float* __restrict__ Wm,
               const float* __restrict__ bias, float* __restrict__ out) {
  const int bid = blockIdx.x;
  const int nt  = bid & 7;
  const int mt  = bid >> 3;
  const int seg = mt / 108;
  const int q0  = (mt - seg * 108) * 128;
  const int bb  = seg >> 1;
  const int g   = seg & 1;

  const int tid  = threadIdx.x;
  const int wv   = tid >> 6;
  const int wr   = wv >> 1;
  const int wc   = wv & 1;
  const int lane = tid & 63;
  const int lm   = lane & 15;
  const int quad = lane >> 4;

  const int n0 = nt * 128 + wc * 64;

  int aoff[4];
#pragma unroll
  for (int i = 0; i < 4; i++)
    aoff[i] = (quad * 8) * NSPAT + q0 + wr * 64 + i * 16 + lm;

  const float* wptr[4];
#pragma unroll
  for (int j = 0; j < 4; j++)
    wptr[j] = Wm + (size_t)(n0 + j * 16 + lm) * 1024 + quad * 8;

  f32x4 acc[4][4];
#pragma unroll
  for (int i = 0; i < 4; i++)
#pragma unroll
    for (int j = 0; j < 4; j++) {
      f32x4 z = {0.f, 0.f, 0.f, 0.f};
      acc[i][j] = z;
    }

  const float* xb = x + (size_t)bb * 32 * NSPAT;

  for (int kc = 0; kc < 32; kc++) {
    const int t_src = ((g << 5) + kc + 48) & 63;
    const float* xs = xb + (size_t)t_src * QQ;

    bf16x8 af[4];
#pragma unroll
    for (int i = 0; i < 4; i++) {
      float v[8];
#pragma unroll
      for (int t = 0; t < 8; t++)
        v[t] = xs[aoff[i] + t * NSPAT];
      bf16x8 f;
#pragma unroll
      for (int t = 0; t < 8; t++) f[t] = f2bf(v[t]);
      af[i] = f;
    }

    bf16x8 bfr[4];
#pragma unroll
    for (int j = 0; j < 4; j++) {
      const float* wp = wptr[j] + kc * 32;
      const f32x4 w0 = *(const f32x4*)(wp);
      const f32x4 w1 = *(const f32x4*)(wp + 4);
      bf16x8 f;
#pragma unroll
      for (int t = 0; t < 4; t++) { f[t] = f2bf(w0[t]); f[t + 4] = f2bf(w1[t]); }
      bfr[j] = f;
    }

#pragma unroll
    for (int i = 0; i < 4; i++)
#pragma unroll
      for (int j = 0; j < 4; j++)
        acc[i][j] = __builtin_amdgcn_mfma_f32_16x16x32_bf16(af[i], bfr[j], acc[i][j], 0, 0, 0);
  }

  float* ob = out + (size_t)bb * 32 * NSPAT;
#pragma unroll
  for (int j = 0; j < 4; j++) {
    const int o  = n0 + j * 16 + lm;
    const float bv = bias[o];
    const int so = o >> 5;
    const int cc = o & 31;
    const int tt = ((g << 5) + so + 48) & 63;
    float* orow = ob + (size_t)cc * NSPAT + (size_t)tt * QQ + q0;
#pragma unroll
    for (int i = 0; i < 4; i++) {
      const int mb = wr * 64 + i * 16 + quad * 4;
      f32x4 v = acc[i][j];
      v += bv;
      *(f32x4*)(orow + mb) = v;
    }
  }
}

extern "C" void kernel_launch(void* const* d_in, const int* in_sizes, int n_in,
                              void* d_out, int out_size, void* d_ws, size_t ws_size,
                              hipStream_t stream) {
  const float* x    = (const float*)d_in[0];
  const float* Wm   = (const float*)d_in[1];
  const float* bias = (const float*)d_in[2];
  float* out        = (float*)d_out;

  const size_t need = (size_t)MTOT * KK * 2 + (size_t)KK * KK * 2;  // 115.3 MB
  if (ws_size >= need) {
    short* Abf = (short*)d_ws;
    short* Wbf = (short*)d_ws + (size_t)MTOT * KK;
    convert_pre<<<dim3(NBLK_A + NBLK_W), dim3(256), 0, stream>>>(x, Wm, Abf, Wbf);
    swin_mfma<<<dim3(432 * 8), dim3(256), 0, stream>>>(Abf, Wbf, bias, out);
  } else {
    swin_gemm<<<dim3(432 * 8), dim3(256), 0, stream>>>(x, Wm, bias, out);
  }
}